// Round 1
// 328.897 us; speedup vs baseline: 1.0254x; 1.0254x over previous
//
#include <hip/hip_runtime.h>

#define NB 8
#define NC 256
#define DF 16384
#define KCL 16
#define SPLITS 16
#define KC (DF / SPLITS)     // 1024
#define BK 32
#define ITERS (KC / BK)      // 32
#define NPAIR 3              // 128x128 upper-tri pairs: (0,0),(0,1),(1,1)
#define GEMM_BLOCKS (NPAIR * 2 * NB * SPLITS)   // 6*8*16 = 768

typedef _Float16 half8 __attribute__((ext_vector_type(8)));
typedef _Float16 half4_t __attribute__((ext_vector_type(4)));
typedef float floatx4 __attribute__((ext_vector_type(4)));

__device__ const int TItab[NPAIR] = {0,0,1};
__device__ const int TJtab[NPAIR] = {0,1,1};

// ---------------- argmax over 256 threads (first occurrence) ---------------------
__device__ __forceinline__ int argmax256(float v, float* sv, int* si) {
  int t = threadIdx.x;
  sv[t] = v; si[t] = t;
  __syncthreads();
  #pragma unroll
  for (int s = 128; s >= 1; s >>= 1) {
    if (t < s) {
      float a = sv[t], b = sv[t + s];
      int ia = si[t], ib = si[t + s];
      if (b > a || (b == a && ib < ia)) { sv[t] = b; si[t] = ib; }
    }
    __syncthreads();
  }
  int r = si[0];
  __syncthreads();
  return r;
}

// ---------------- argmax over 512 threads via pointers (first occurrence) --------
__device__ __forceinline__ int argmax512p(float v, float* sv, int* si) {
  int t = threadIdx.x;
  sv[t] = v; si[t] = t;
  __syncthreads();
  #pragma unroll
  for (int s = 256; s >= 1; s >>= 1) {
    if (t < s) {
      float a = sv[t], b = sv[t + s];
      int ia = si[t], ib = si[t + s];
      if (b > a || (b == a && ib < ia)) { sv[t] = b; si[t] = ib; }
    }
    __syncthreads();
  }
  int r = si[0];
  __syncthreads();
  return r;
}

// ---------------- K1: fused [gemm 768 blocks | pos-FPS block 768] ----------------
// gemm: 128x64 col-half tiles of the upper-tri pairs, 3 f16 chains (hi/lo split)
// Block remap: xcd = bid&7 (HW round-robin). All 6 blocks of one (b,sp) group land
// on the SAME XCD so the 3.5x tile-load redundancy hits that XCD's L2 instead of
// streaming over the Infinity Cache (which was the 18 TB/s bottleneck).
__global__ __launch_bounds__(512, 3) void k_gemm_pre(const float* __restrict__ ff,
                                                     const float* __restrict__ pe,
                                                     float* __restrict__ Pp,
                                                     float* __restrict__ centers0,
                                                     float* __restrict__ rs) {
  __shared__ _Float16 Ah[128][40];   // pad 32->40: frag reads 2-way bank alias (free)
  __shared__ _Float16 Al[128][40];
  __shared__ _Float16 Bh[64][40];
  __shared__ _Float16 Bl[64][40];

  const int bid = blockIdx.x;
  const int tid = threadIdx.x;

  if (bid == GEMM_BLOCKS) {
    // ---- pos-FPS (512 threads; arrays aliased onto gemm LDS) ----
    float* sm = (float*)&Ah[0][0];
    float* px = sm;        float* py = sm + 256;
    float* pz = sm + 512;  float* pn = sm + 768;
    float* sv = sm + 1024; int*   si = (int*)(sm + 1536);
    int* fpsIdx = (int*)(sm + 2048);
    const int t = tid;
    for (int i = t; i < NB * NC; i += 512) rs[i] = 0.f;   // zero rs (ws poisoned)
    const bool valid = t < NC;
    float x = 0.f, y = 0.f, z = 0.f, n = 0.f;
    if (valid) {
      x = pe[t * 3 + 0]; y = pe[t * 3 + 1]; z = pe[t * 3 + 2];
      n = x * x + y * y + z * z;
      px[t] = x; py[t] = y; pz[t] = z; pn[t] = n;
    }
    __syncthreads();
    float rsum = -3.4e38f;
    if (valid) {
      rsum = 0.f;
      for (int j = 0; j < NC; ++j) {
        float dot = x * px[j] + y * py[j] + z * pz[j];
        rsum += sqrtf(fmaxf(n + pn[j] - 2.f * dot, 0.f));
      }
    }
    int start = argmax512p(rsum, sv, si);
    if (t == 0) fpsIdx[0] = start;
    float mind = -3.4e38f;
    if (valid) {
      float dot0 = x * px[start] + y * py[start] + z * pz[start];
      mind = sqrtf(fmaxf(n + pn[start] - 2.f * dot0, 0.f));
    }
    for (int it = 1; it < KCL; ++it) {
      int far = argmax512p(mind, sv, si);
      if (t == 0) fpsIdx[it] = far;
      if (valid) {
        float dot = x * px[far] + y * py[far] + z * pz[far];
        mind = fminf(mind, sqrtf(fmaxf(n + pn[far] - 2.f * dot, 0.f)));
      }
    }
    __syncthreads();
    if (t < KCL) {
      int p = fpsIdx[t];
      centers0[t * 3 + 0] = px[p];
      centers0[t * 3 + 1] = py[p];
      centers0[t * 3 + 2] = pz[p];
    }
    return;
  }

  // ---- gemm block ----
  // XCD-aware remap: keep all 6 tc-blocks of a (b,sp) group on one XCD.
  // bid -> (x = XCD, slot within XCD); slot -> (group u, tc); gi = x*16+u -> (b,sp).
  // Bijective: 768 = 8 XCD * 16 groups * 6 tc.
  const int x    = bid & 7;
  const int slot = bid >> 3;      // 0..95
  const int tc   = slot % 6;
  const int u    = slot / 6;      // 0..15
  const int gi   = x * 16 + u;    // 0..127
  const int b    = gi & 7;
  const int sp   = gi >> 3;

  const int pair = tc >> 1, ch = tc & 1;
  const int ti = TItab[pair], tj = TJtab[pair];
  const bool diag = (ti == tj);

  const int wave = tid >> 6, lane = tid & 63;
  const int wr = wave >> 1, wc = wave & 1;    // 8 waves: 4 row-strips x 2 col-strips
  const int lrow = lane & 15, q = lane >> 4;

  // A staging: 128 rows x 32 cols, 8 floats/thread
  const int srA = tid >> 2, scA = (tid & 3) * 8;
  // B staging: 64 rows x 32 cols, 4 floats/thread
  const int srB = tid >> 3, scB = (tid & 7) * 4;
  const float* gA = ff + ((size_t)(b * NC + ti * 128 + srA)) * DF + sp * KC + scA;
  const float* gB = ff + ((size_t)(b * NC + tj * 128 + ch * 64 + srB)) * DF + sp * KC + scB;

  floatx4 a1[2][2], a2[2][2], a3[2][2];
  #pragma unroll
  for (int i = 0; i < 2; ++i)
    #pragma unroll
    for (int j = 0; j < 2; ++j) { a1[i][j] = (floatx4)0.f; a2[i][j] = (floatx4)0.f; a3[i][j] = (floatx4)0.f; }

  float4 ra0 = *(const float4*)(gA), ra1 = *(const float4*)(gA + 4);
  float4 rb = make_float4(0.f, 0.f, 0.f, 0.f);
  if (!diag) rb = *(const float4*)(gB);
  gA += BK; gB += BK;

  for (int it = 0; it < ITERS; ++it) {
    float fa[8] = {ra0.x, ra0.y, ra0.z, ra0.w, ra1.x, ra1.y, ra1.z, ra1.w};
    half8 ah, al;
    #pragma unroll
    for (int e = 0; e < 8; ++e) {
      _Float16 h = (_Float16)fa[e];
      ah[e] = h;
      al[e] = (_Float16)(fa[e] - (float)h);
    }
    half4_t bh4, bl4;
    if (!diag) {
      float fb[4] = {rb.x, rb.y, rb.z, rb.w};
      #pragma unroll
      for (int e = 0; e < 4; ++e) {
        _Float16 h = (_Float16)fb[e];
        bh4[e] = h;
        bl4[e] = (_Float16)(fb[e] - (float)h);
      }
    }
    __syncthreads();   // previous iter's frag reads complete
    *(half8*)&Ah[srA][scA] = ah;
    *(half8*)&Al[srA][scA] = al;
    if (!diag) {
      *(half4_t*)&Bh[srB][scB] = bh4;
      *(half4_t*)&Bl[srB][scB] = bl4;
    }
    __syncthreads();   // tiles visible
    if (it + 1 < ITERS) {
      ra0 = *(const float4*)(gA); ra1 = *(const float4*)(gA + 4);
      if (!diag) rb = *(const float4*)(gB);
      gA += BK; gB += BK;
    }
    // diag blocks read B-frags from the A tile at row offset ch*64 (same stride 40)
    const _Float16* bhp = diag ? &Ah[ch * 64][0] : &Bh[0][0];
    const _Float16* blp = diag ? &Al[ch * 64][0] : &Bl[0][0];
    half8 af[2], lf[2];
    #pragma unroll
    for (int i = 0; i < 2; ++i) {
      af[i] = *(const half8*)&Ah[wr * 32 + i * 16 + lrow][q * 8];
      lf[i] = *(const half8*)&Al[wr * 32 + i * 16 + lrow][q * 8];
    }
    #pragma unroll
    for (int j = 0; j < 2; ++j) {
      half8 bhf = *(const half8*)(bhp + (wc * 32 + j * 16 + lrow) * 40 + q * 8);
      half8 blf = *(const half8*)(blp + (wc * 32 + j * 16 + lrow) * 40 + q * 8);
      #pragma unroll
      for (int i = 0; i < 2; ++i) {
        a1[i][j] = __builtin_amdgcn_mfma_f32_16x16x32_f16(af[i], bhf, a1[i][j], 0, 0, 0);
        a2[i][j] = __builtin_amdgcn_mfma_f32_16x16x32_f16(af[i], blf, a2[i][j], 0, 0, 0);
        a3[i][j] = __builtin_amdgcn_mfma_f32_16x16x32_f16(lf[i], bhf, a3[i][j], 0, 0, 0);
      }
    }
  }

  // epilogue: S = a1+a2+a3. Diag 128x128 blocks fully covered by both halves -> no mirror.
  float* Pb = Pp + (size_t)(sp * NB + b) * NC * NC;
  #pragma unroll
  for (int i = 0; i < 2; ++i) {
    int grow = ti * 128 + wr * 32 + i * 16 + q * 4;
    #pragma unroll
    for (int j = 0; j < 2; ++j) {
      int gcol = tj * 128 + ch * 64 + wc * 32 + j * 16 + lrow;
      float4 v;
      v.x = a1[i][j][0] + a2[i][j][0] + a3[i][j][0];
      v.y = a1[i][j][1] + a2[i][j][1] + a3[i][j][1];
      v.z = a1[i][j][2] + a2[i][j][2] + a3[i][j][2];
      v.w = a1[i][j][3] + a2[i][j][3] + a3[i][j][3];
      Pb[(size_t)(grow + 0) * NC + gcol] = v.x;
      Pb[(size_t)(grow + 1) * NC + gcol] = v.y;
      Pb[(size_t)(grow + 2) * NC + gcol] = v.z;
      Pb[(size_t)(grow + 3) * NC + gcol] = v.w;
      if (!diag) *(float4*)&Pb[(size_t)gcol * NC + grow] = v;  // mirror (lower block)
    }
  }
}

// ---------------- K2: diag + formD + column partial sums (fused) -----------------
__global__ __launch_bounds__(256) void k_formD(const float* __restrict__ Pp,
                                               float* __restrict__ Db,
                                               float* __restrict__ rs) {
  __shared__ float dg_s[NC];
  const int t = threadIdx.x;
  const int b = blockIdx.x >> 5, i0 = (blockIdx.x & 31) * 8;
  float s = 0.f;
  #pragma unroll
  for (int sp = 0; sp < SPLITS; ++sp)
    s += Pp[((size_t)(sp * NB + b) * NC + t) * NC + t];
  dg_s[t] = s;
  __syncthreads();
  float colsum = 0.f;
  for (int ii = 0; ii < 8; ++ii) {
    int i = i0 + ii;
    float acc = 0.f;
    #pragma unroll
    for (int sp = 0; sp < SPLITS; ++sp)
      acc += Pp[((size_t)(sp * NB + b) * NC + i) * NC + t];
    float d2 = dg_s[i] + dg_s[t] - 2.f * acc;
    float d = sqrtf(fmaxf(d2, 0.f));
    Db[((size_t)b * NC + i) * NC + t] = d;
    colsum += d;
  }
  atomicAdd(&rs[b * NC + t], colsum);
}

// ---------------- K3: per-batch FPS on Db (8 blocks), rs precomputed -------------
__global__ __launch_bounds__(256) void k_fps_b(const float* __restrict__ Db,
                                               const float* __restrict__ rs,
                                               const float* __restrict__ pe,
                                               float* __restrict__ ccoord) {
  int b = blockIdx.x, t = threadIdx.x;
  const float* D = Db + (size_t)b * NC * NC;
  __shared__ float sv[NC]; __shared__ int si[NC];
  __shared__ int fpsIdx[KCL];
  int start = argmax256(rs[b * NC + t], sv, si);
  if (t == 0) fpsIdx[0] = start;
  float mind = D[start * NC + t];   // symmetric row==col
  for (int it = 1; it < KCL; ++it) {
    int far = argmax256(mind, sv, si);
    if (t == 0) fpsIdx[it] = far;
    mind = fminf(mind, D[far * NC + t]);
  }
  __syncthreads();
  if (t < KCL) {
    int p = fpsIdx[t];
    ccoord[(b * KCL + t) * 3 + 0] = pe[(b * NC + p) * 3 + 0];
    ccoord[(b * KCL + t) * 3 + 1] = pe[(b * NC + p) * 3 + 1];
    ccoord[(b * KCL + t) * 3 + 2] = pe[(b * NC + p) * 3 + 2];
  }
}

// ---------------- K4: temp_assign + seg-means + matching + update + capacity -----
__global__ __launch_bounds__(256) void k_final(const float* __restrict__ pe,
                                               const float* __restrict__ ccoord,
                                               const float* __restrict__ centers0,
                                               int* __restrict__ outp) {
  __shared__ float cc[NB * KCL * 3];
  __shared__ float cn[NB * KCL];
  __shared__ float sums[KCL][3];
  __shared__ int cnts[KCL];
  __shared__ float avg[KCL][3];
  __shared__ float an[KCL];
  __shared__ float c0[KCL * 3];
  __shared__ float c1x[KCL], c1y[KCL], c1z[KCL], c1n[KCL];
  __shared__ int order[NC][KCL];
  int t = threadIdx.x;
  for (int i = t; i < NB * KCL * 3; i += 256) cc[i] = ccoord[i];
  if (t < KCL * 3) c0[t] = centers0[t];
  if (t < KCL) { sums[t][0] = 0.f; sums[t][1] = 0.f; sums[t][2] = 0.f; cnts[t] = 0; }
  __syncthreads();
  if (t < NB * KCL) {
    float x = cc[t * 3], y = cc[t * 3 + 1], z = cc[t * 3 + 2];
    cn[t] = x * x + y * y + z * z;
  }
  __syncthreads();
  for (int b = 0; b < NB; ++b) {
    int p = b * NC + t;
    float x = pe[p * 3], y = pe[p * 3 + 1], z = pe[p * 3 + 2];
    float n = x * x + y * y + z * z;
    float best = 3.4e38f; int bi = 0;
    #pragma unroll
    for (int k = 0; k < KCL; ++k) {
      int c = b * KCL + k;
      float dot = x * cc[c * 3] + y * cc[c * 3 + 1] + z * cc[c * 3 + 2];
      float d2 = fmaxf(n + cn[c] - 2.f * dot, 0.f);
      if (d2 < best) { best = d2; bi = k; }
    }
    atomicAdd(&sums[bi][0], x);
    atomicAdd(&sums[bi][1], y);
    atomicAdd(&sums[bi][2], z);
    atomicAdd(&cnts[bi], 1);
  }
  __syncthreads();
  if (t < KCL) {
    float c = (float)cnts[t];
    float inv = 1.f / fmaxf(c, 1.f);
    float ax = (cnts[t] > 0) ? sums[t][0] * inv : 0.f;
    float ay = (cnts[t] > 0) ? sums[t][1] * inv : 0.f;
    float az = (cnts[t] > 0) ? sums[t][2] * inv : 0.f;
    avg[t][0] = ax; avg[t][1] = ay; avg[t][2] = az;
    an[t] = ax * ax + ay * ay + az * az;
  }
  __syncthreads();
  if (t < KCL) {
    float x = c0[t * 3], y = c0[t * 3 + 1], z = c0[t * 3 + 2];
    float n = x * x + y * y + z * z;
    float best = 3.4e38f; int bi = 0;
    #pragma unroll
    for (int j = 0; j < KCL; ++j) {
      float dot = x * avg[j][0] + y * avg[j][1] + z * avg[j][2];
      float d2 = fmaxf(n + an[j] - 2.f * dot, 0.f);
      if (d2 < best) { best = d2; bi = j; }
    }
    float nx = 0.8f * x + 0.2f * avg[bi][0];
    float ny = 0.8f * y + 0.2f * avg[bi][1];
    float nz = 0.8f * z + 0.2f * avg[bi][2];
    c1x[t] = nx; c1y[t] = ny; c1z[t] = nz;
    c1n[t] = nx * nx + ny * ny + nz * nz;
  }
  __syncthreads();
  {
    float x = pe[t * 3], y = pe[t * 3 + 1], z = pe[t * 3 + 2];
    float n = x * x + y * y + z * z;
    float v[KCL];
    #pragma unroll
    for (int k = 0; k < KCL; ++k) {
      float dot = x * c1x[k] + y * c1y[k] + z * c1z[k];
      v[k] = fmaxf(n + c1n[k] - 2.f * dot, 0.f);
    }
    bool used[KCL];
    #pragma unroll
    for (int k = 0; k < KCL; ++k) used[k] = false;
    for (int r = 0; r < KCL; ++r) {
      float best = 3.4e38f; int bi = 0;
      #pragma unroll
      for (int j = 0; j < KCL; ++j) {
        if (!used[j] && v[j] < best) { best = v[j]; bi = j; }
      }
      order[t][r] = bi;
      used[bi] = true;
    }
  }
  __syncthreads();
  if (t < 64) {
    int cnt = 0;
    int cur = (t < KCL) ? order[0][t] : 0;
    for (int i = 0; i < NC; ++i) {
      int nxt = (t < KCL && i + 1 < NC) ? order[i + 1][t] : 0;
      int ccur = __shfl(cnt, cur);
      bool avail = (t < KCL) && (ccur < 16);
      unsigned long long m = __ballot(avail);
      int chosen;
      if (m != 0ull) {
        int rank = __ffsll((unsigned long long)m) - 1;
        chosen = __shfl(cur, rank);
      } else {
        chosen = __shfl(cur, 0);
      }
      if (t == chosen) cnt++;
      if (t == 0) outp[i] = chosen;
      cur = nxt;
    }
  }
}

extern "C" void kernel_launch(void* const* d_in, const int* in_sizes, int n_in,
                              void* d_out, int out_size, void* d_ws, size_t ws_size,
                              hipStream_t stream) {
  (void)in_sizes; (void)n_in; (void)out_size; (void)ws_size;
  const float* features = (const float*)d_in[0];
  const float* pe = (const float*)d_in[1];
  char* ws = (char*)d_ws;
  float* Pp       = (float*)(ws);                  // 16*8*256*256*4 = 32 MiB
  float* Db       = (float*)(ws + 33554432);       // 2 MiB
  float* rs       = (float*)(ws + 35651584);       // 8 KiB
  float* centers0 = (float*)(ws + 35659776);       // 192 B
  float* ccoord   = (float*)(ws + 35660288);       // 1.5 KiB
  int*   outp     = (int*)d_out;

  hipLaunchKernelGGL(k_gemm_pre, dim3(GEMM_BLOCKS + 1), dim3(512), 0, stream,
                     features, pe, Pp, centers0, rs);
  hipLaunchKernelGGL(k_formD, dim3(256), dim3(256), 0, stream, Pp, Db, rs);
  hipLaunchKernelGGL(k_fps_b, dim3(NB), dim3(256), 0, stream, Db, rs, pe, ccoord);
  hipLaunchKernelGGL(k_final, dim3(1), dim3(256), 0, stream, pe, ccoord, centers0, outp);
}

// Round 3
// 324.036 us; speedup vs baseline: 1.0408x; 1.0150x over previous
//
#include <hip/hip_runtime.h>

#define NB 8
#define NC 256
#define DF 16384
#define KCL 16
#define SPLITS 16
#define KC (DF / SPLITS)     // 1024
#define BK 32
#define ITERS (KC / BK)      // 32
#define NPAIR 3              // 128x128 upper-tri pairs: (0,0),(0,1),(1,1)
#define GEMM_BLOCKS (NPAIR * 2 * NB * SPLITS)   // 6*8*16 = 768

typedef _Float16 half8 __attribute__((ext_vector_type(8)));
typedef _Float16 half4_t __attribute__((ext_vector_type(4)));
typedef float floatx4 __attribute__((ext_vector_type(4)));

__device__ const int TItab[NPAIR] = {0,0,1};
__device__ const int TJtab[NPAIR] = {0,1,1};

// ------------- argmax over 256 threads: wave-shuffle + 2 barriers ---------------
// first-occurrence semantics (ties -> smallest index), matches jnp.argmax
__device__ __forceinline__ int argmax256w(float v, float* sv, int* si) {
  int t = threadIdx.x;
  float bv = v; int bi = t;
  #pragma unroll
  for (int s = 32; s >= 1; s >>= 1) {
    float ov = __shfl_down(bv, s);
    int   oi = __shfl_down(bi, s);
    if (ov > bv || (ov == bv && oi < bi)) { bv = ov; bi = oi; }
  }
  int w = t >> 6;
  if ((t & 63) == 0) { sv[w] = bv; si[w] = bi; }
  __syncthreads();
  float rbv = sv[0]; int rbi = si[0];
  #pragma unroll
  for (int k = 1; k < 4; ++k) {
    float ov = sv[k]; int oi = si[k];
    if (ov > rbv || (ov == rbv && oi < rbi)) { rbv = ov; rbi = oi; }
  }
  __syncthreads();   // protect sv/si for next call
  return rbi;
}

// ---------------- K1: fused [gemm 768 blocks | pos-FPS block 768] ----------------
// gemm: 128x64 col-half tiles, 4 waves x (64x32) wave-tile, 3 f16 chains with the
// two correction chains (Ah*Bl + Al*Bh) merged into ONE accumulator (linear sum).
// XCD remap keeps the 6 blocks of a (b,sp) group on one XCD (L2 reuse, round 1).
__global__ __launch_bounds__(256, 3) void k_gemm_pre(const float* __restrict__ ff,
                                                     const float* __restrict__ pe,
                                                     float* __restrict__ Pp,
                                                     float* __restrict__ centers0,
                                                     float* __restrict__ rs) {
  __shared__ _Float16 Ah[128][40];   // pad 32->40: frag reads 2-way bank alias (free)
  __shared__ _Float16 Al[128][40];
  __shared__ _Float16 Bh[64][40];
  __shared__ _Float16 Bl[64][40];

  const int bid = blockIdx.x;
  const int tid = threadIdx.x;

  if (bid == GEMM_BLOCKS) {
    // ---- pos-FPS (256 threads; arrays aliased onto gemm LDS) ----
    float* sm = (float*)&Ah[0][0];
    float* px = sm;        float* py = sm + 256;
    float* pz = sm + 512;  float* pn = sm + 768;
    float* sv = sm + 1024; int*   si = (int*)(sm + 1280);
    int* fpsIdx = (int*)(sm + 1536);
    const int t = tid;
    for (int i = t; i < NB * NC; i += 256) rs[i] = 0.f;   // zero rs (ws poisoned)
    float x = pe[t * 3 + 0], y = pe[t * 3 + 1], z = pe[t * 3 + 2];
    float n = x * x + y * y + z * z;
    px[t] = x; py[t] = y; pz[t] = z; pn[t] = n;
    __syncthreads();
    float rsum = 0.f;
    for (int j = 0; j < NC; ++j) {
      float dot = x * px[j] + y * py[j] + z * pz[j];
      rsum += sqrtf(fmaxf(n + pn[j] - 2.f * dot, 0.f));
    }
    int start = argmax256w(rsum, sv, si);
    if (t == 0) fpsIdx[0] = start;
    float dot0 = x * px[start] + y * py[start] + z * pz[start];
    float mind = sqrtf(fmaxf(n + pn[start] - 2.f * dot0, 0.f));
    for (int it = 1; it < KCL; ++it) {
      int far = argmax256w(mind, sv, si);
      if (t == 0) fpsIdx[it] = far;
      float dot = x * px[far] + y * py[far] + z * pz[far];
      mind = fminf(mind, sqrtf(fmaxf(n + pn[far] - 2.f * dot, 0.f)));
    }
    __syncthreads();
    if (t < KCL) {
      int p = fpsIdx[t];
      centers0[t * 3 + 0] = px[p];
      centers0[t * 3 + 1] = py[p];
      centers0[t * 3 + 2] = pz[p];
    }
    return;
  }

  // ---- gemm block ----
  // XCD-aware remap (bijective: 768 = 8 XCD * 16 groups * 6 tc).
  const int x    = bid & 7;
  const int slot = bid >> 3;      // 0..95
  const int tc   = slot % 6;
  const int u    = slot / 6;      // 0..15
  const int gi   = x * 16 + u;    // 0..127
  const int b    = gi & 7;
  const int sp   = gi >> 3;

  const int pair = tc >> 1, ch = tc & 1;
  const int ti = TItab[pair], tj = TJtab[pair];
  const bool diag = (ti == tj);

  const int wave = tid >> 6, lane = tid & 63;
  const int wr = wave >> 1, wc = wave & 1;    // 4 waves: 2 row-strips(64) x 2 col-strips(32)
  const int lrow = lane & 15, q = lane >> 4;

  // A staging: 128x32 = 16 f32/thread (rows srA and srA+64, 8 cols each)
  const int srA = tid >> 2, scA = (tid & 3) * 8;
  // B staging: 64x32 = 8 f32/thread
  const int srB = tid >> 2, scB = (tid & 3) * 8;
  const float* gA0 = ff + ((size_t)(b * NC + ti * 128 + srA)) * DF + sp * KC + scA;
  const float* gA1 = gA0 + (size_t)64 * DF;
  const float* gB  = ff + ((size_t)(b * NC + tj * 128 + ch * 64 + srB)) * DF + sp * KC + scB;

  floatx4 a1[4][2], c23[4][2];
  #pragma unroll
  for (int i = 0; i < 4; ++i)
    #pragma unroll
    for (int j = 0; j < 2; ++j) { a1[i][j] = (floatx4)0.f; c23[i][j] = (floatx4)0.f; }

  float4 ra0 = *(const float4*)(gA0), ra1 = *(const float4*)(gA0 + 4);
  float4 ra2 = *(const float4*)(gA1), ra3 = *(const float4*)(gA1 + 4);
  float4 rb0 = make_float4(0.f, 0.f, 0.f, 0.f), rb1 = rb0;
  if (!diag) { rb0 = *(const float4*)(gB); rb1 = *(const float4*)(gB + 4); }
  gA0 += BK; gA1 += BK; gB += BK;

  for (int it = 0; it < ITERS; ++it) {
    half8 ah0, al0, ah1, al1;
    half8 bh8 = (half8)(_Float16)0.f, bl8 = (half8)(_Float16)0.f;
    {
      float f[8] = {ra0.x, ra0.y, ra0.z, ra0.w, ra1.x, ra1.y, ra1.z, ra1.w};
      #pragma unroll
      for (int e = 0; e < 8; ++e) {
        _Float16 h = (_Float16)f[e];
        ah0[e] = h; al0[e] = (_Float16)(f[e] - (float)h);
      }
    }
    {
      float f[8] = {ra2.x, ra2.y, ra2.z, ra2.w, ra3.x, ra3.y, ra3.z, ra3.w};
      #pragma unroll
      for (int e = 0; e < 8; ++e) {
        _Float16 h = (_Float16)f[e];
        ah1[e] = h; al1[e] = (_Float16)(f[e] - (float)h);
      }
    }
    if (!diag) {
      float f[8] = {rb0.x, rb0.y, rb0.z, rb0.w, rb1.x, rb1.y, rb1.z, rb1.w};
      #pragma unroll
      for (int e = 0; e < 8; ++e) {
        _Float16 h = (_Float16)f[e];
        bh8[e] = h; bl8[e] = (_Float16)(f[e] - (float)h);
      }
    }
    __syncthreads();   // previous iter's frag reads complete
    *(half8*)&Ah[srA][scA] = ah0;
    *(half8*)&Al[srA][scA] = al0;
    *(half8*)&Ah[srA + 64][scA] = ah1;
    *(half8*)&Al[srA + 64][scA] = al1;
    if (!diag) {
      *(half8*)&Bh[srB][scB] = bh8;
      *(half8*)&Bl[srB][scB] = bl8;
    }
    __syncthreads();   // tiles visible
    if (it + 1 < ITERS) {
      ra0 = *(const float4*)(gA0); ra1 = *(const float4*)(gA0 + 4);
      ra2 = *(const float4*)(gA1); ra3 = *(const float4*)(gA1 + 4);
      if (!diag) { rb0 = *(const float4*)(gB); rb1 = *(const float4*)(gB + 4); }
      gA0 += BK; gA1 += BK; gB += BK;
    }
    // diag blocks read B-frags from the A tile at row offset ch*64 (same stride 40)
    const _Float16* bhp = diag ? &Ah[ch * 64][0] : &Bh[0][0];
    const _Float16* blp = diag ? &Al[ch * 64][0] : &Bl[0][0];
    half8 bhf[2], blf[2];
    #pragma unroll
    for (int j = 0; j < 2; ++j) {
      bhf[j] = *(const half8*)(bhp + (wc * 32 + j * 16 + lrow) * 40 + q * 8);
      blf[j] = *(const half8*)(blp + (wc * 32 + j * 16 + lrow) * 40 + q * 8);
    }
    __builtin_amdgcn_s_setprio(1);
    #pragma unroll
    for (int i = 0; i < 4; ++i) {
      half8 a_h = *(const half8*)&Ah[wr * 64 + i * 16 + lrow][q * 8];
      half8 a_l = *(const half8*)&Al[wr * 64 + i * 16 + lrow][q * 8];
      #pragma unroll
      for (int j = 0; j < 2; ++j) {
        a1[i][j]  = __builtin_amdgcn_mfma_f32_16x16x32_f16(a_h, bhf[j], a1[i][j], 0, 0, 0);
        c23[i][j] = __builtin_amdgcn_mfma_f32_16x16x32_f16(a_h, blf[j], c23[i][j], 0, 0, 0);
        c23[i][j] = __builtin_amdgcn_mfma_f32_16x16x32_f16(a_l, bhf[j], c23[i][j], 0, 0, 0);
      }
    }
    __builtin_amdgcn_s_setprio(0);
  }

  // epilogue: S = a1 + c23. Diag 128x128 blocks fully covered by both halves -> no mirror.
  float* Pb = Pp + (size_t)(sp * NB + b) * NC * NC;
  #pragma unroll
  for (int i = 0; i < 4; ++i) {
    int grow = ti * 128 + wr * 64 + i * 16 + q * 4;
    #pragma unroll
    for (int j = 0; j < 2; ++j) {
      int gcol = tj * 128 + ch * 64 + wc * 32 + j * 16 + lrow;
      float4 v;
      v.x = a1[i][j][0] + c23[i][j][0];
      v.y = a1[i][j][1] + c23[i][j][1];
      v.z = a1[i][j][2] + c23[i][j][2];
      v.w = a1[i][j][3] + c23[i][j][3];
      Pb[(size_t)(grow + 0) * NC + gcol] = v.x;
      Pb[(size_t)(grow + 1) * NC + gcol] = v.y;
      Pb[(size_t)(grow + 2) * NC + gcol] = v.z;
      Pb[(size_t)(grow + 3) * NC + gcol] = v.w;
      if (!diag) *(float4*)&Pb[(size_t)gcol * NC + grow] = v;  // mirror (lower block)
    }
  }
}

// ---------------- K2: diag + formD + column partial sums (fused) -----------------
__global__ __launch_bounds__(256) void k_formD(const float* __restrict__ Pp,
                                               float* __restrict__ Db,
                                               float* __restrict__ rs) {
  __shared__ float dg_s[NC];
  const int t = threadIdx.x;
  const int b = blockIdx.x >> 5, i0 = (blockIdx.x & 31) * 8;
  float s = 0.f;
  #pragma unroll
  for (int sp = 0; sp < SPLITS; ++sp)
    s += Pp[((size_t)(sp * NB + b) * NC + t) * NC + t];
  dg_s[t] = s;
  __syncthreads();
  float colsum = 0.f;
  for (int ii = 0; ii < 8; ++ii) {
    int i = i0 + ii;
    float acc = 0.f;
    #pragma unroll
    for (int sp = 0; sp < SPLITS; ++sp)
      acc += Pp[((size_t)(sp * NB + b) * NC + i) * NC + t];
    float d2 = dg_s[i] + dg_s[t] - 2.f * acc;
    float d = sqrtf(fmaxf(d2, 0.f));
    Db[((size_t)b * NC + i) * NC + t] = d;
    colsum += d;
  }
  atomicAdd(&rs[b * NC + t], colsum);
}

// ---------------- K3: per-batch FPS on Db (8 blocks), rs precomputed -------------
__global__ __launch_bounds__(256) void k_fps_b(const float* __restrict__ Db,
                                               const float* __restrict__ rs,
                                               const float* __restrict__ pe,
                                               float* __restrict__ ccoord) {
  int b = blockIdx.x, t = threadIdx.x;
  const float* D = Db + (size_t)b * NC * NC;
  __shared__ float sv[4]; __shared__ int si[4];
  __shared__ int fpsIdx[KCL];
  int start = argmax256w(rs[b * NC + t], sv, si);
  if (t == 0) fpsIdx[0] = start;
  float mind = D[start * NC + t];   // symmetric row==col
  for (int it = 1; it < KCL; ++it) {
    int far = argmax256w(mind, sv, si);
    if (t == 0) fpsIdx[it] = far;
    mind = fminf(mind, D[far * NC + t]);
  }
  __syncthreads();
  if (t < KCL) {
    int p = fpsIdx[t];
    ccoord[(b * KCL + t) * 3 + 0] = pe[(b * NC + p) * 3 + 0];
    ccoord[(b * KCL + t) * 3 + 1] = pe[(b * NC + p) * 3 + 1];
    ccoord[(b * KCL + t) * 3 + 2] = pe[(b * NC + p) * 3 + 2];
  }
}

// ---------------- K4: temp_assign + seg-means + matching + update + capacity -----
__global__ __launch_bounds__(256) void k_final(const float* __restrict__ pe,
                                               const float* __restrict__ ccoord,
                                               const float* __restrict__ centers0,
                                               int* __restrict__ outp) {
  __shared__ float cc[NB * KCL * 3];
  __shared__ float cn[NB * KCL];
  __shared__ float sums[KCL][3];
  __shared__ int cnts[KCL];
  __shared__ float avg[KCL][3];
  __shared__ float an[KCL];
  __shared__ float c0[KCL * 3];
  __shared__ float c1x[KCL], c1y[KCL], c1z[KCL], c1n[KCL];
  __shared__ int order[NC][KCL];
  int t = threadIdx.x;
  for (int i = t; i < NB * KCL * 3; i += 256) cc[i] = ccoord[i];
  if (t < KCL * 3) c0[t] = centers0[t];
  if (t < KCL) { sums[t][0] = 0.f; sums[t][1] = 0.f; sums[t][2] = 0.f; cnts[t] = 0; }
  __syncthreads();
  if (t < NB * KCL) {
    float x = cc[t * 3], y = cc[t * 3 + 1], z = cc[t * 3 + 2];
    cn[t] = x * x + y * y + z * z;
  }
  __syncthreads();
  for (int b = 0; b < NB; ++b) {
    int p = b * NC + t;
    float x = pe[p * 3], y = pe[p * 3 + 1], z = pe[p * 3 + 2];
    float n = x * x + y * y + z * z;
    float best = 3.4e38f; int bi = 0;
    #pragma unroll
    for (int k = 0; k < KCL; ++k) {
      int c = b * KCL + k;
      float dot = x * cc[c * 3] + y * cc[c * 3 + 1] + z * cc[c * 3 + 2];
      float d2 = fmaxf(n + cn[c] - 2.f * dot, 0.f);
      if (d2 < best) { best = d2; bi = k; }
    }
    atomicAdd(&sums[bi][0], x);
    atomicAdd(&sums[bi][1], y);
    atomicAdd(&sums[bi][2], z);
    atomicAdd(&cnts[bi], 1);
  }
  __syncthreads();
  if (t < KCL) {
    float c = (float)cnts[t];
    float inv = 1.f / fmaxf(c, 1.f);
    float ax = (cnts[t] > 0) ? sums[t][0] * inv : 0.f;
    float ay = (cnts[t] > 0) ? sums[t][1] * inv : 0.f;
    float az = (cnts[t] > 0) ? sums[t][2] * inv : 0.f;
    avg[t][0] = ax; avg[t][1] = ay; avg[t][2] = az;
    an[t] = ax * ax + ay * ay + az * az;
  }
  __syncthreads();
  if (t < KCL) {
    float x = c0[t * 3], y = c0[t * 3 + 1], z = c0[t * 3 + 2];
    float n = x * x + y * y + z * z;
    float best = 3.4e38f; int bi = 0;
    #pragma unroll
    for (int j = 0; j < KCL; ++j) {
      float dot = x * avg[j][0] + y * avg[j][1] + z * avg[j][2];
      float d2 = fmaxf(n + an[j] - 2.f * dot, 0.f);
      if (d2 < best) { best = d2; bi = j; }
    }
    float nx = 0.8f * x + 0.2f * avg[bi][0];
    float ny = 0.8f * y + 0.2f * avg[bi][1];
    float nz = 0.8f * z + 0.2f * avg[bi][2];
    c1x[t] = nx; c1y[t] = ny; c1z[t] = nz;
    c1n[t] = nx * nx + ny * ny + nz * nz;
  }
  __syncthreads();
  {
    float x = pe[t * 3], y = pe[t * 3 + 1], z = pe[t * 3 + 2];
    float n = x * x + y * y + z * z;
    float v[KCL];
    #pragma unroll
    for (int k = 0; k < KCL; ++k) {
      float dot = x * c1x[k] + y * c1y[k] + z * c1z[k];
      v[k] = fmaxf(n + c1n[k] - 2.f * dot, 0.f);
    }
    bool used[KCL];
    #pragma unroll
    for (int k = 0; k < KCL; ++k) used[k] = false;
    for (int r = 0; r < KCL; ++r) {
      float best = 3.4e38f; int bi = 0;
      #pragma unroll
      for (int j = 0; j < KCL; ++j) {
        if (!used[j] && v[j] < best) { best = v[j]; bi = j; }
      }
      order[t][r] = bi;
      used[bi] = true;
    }
  }
  __syncthreads();
  if (t < 64) {
    int cnt = 0;
    int cur = (t < KCL) ? order[0][t] : 0;
    for (int i = 0; i < NC; ++i) {
      int nxt = (t < KCL && i + 1 < NC) ? order[i + 1][t] : 0;
      int ccur = __shfl(cnt, cur);
      bool avail = (t < KCL) && (ccur < 16);
      unsigned long long m = __ballot(avail);
      int chosen;
      if (m != 0ull) {
        int rank = __ffsll((unsigned long long)m) - 1;
        chosen = __shfl(cur, rank);
      } else {
        chosen = __shfl(cur, 0);
      }
      if (t == chosen) cnt++;
      if (t == 0) outp[i] = chosen;
      cur = nxt;
    }
  }
}

extern "C" void kernel_launch(void* const* d_in, const int* in_sizes, int n_in,
                              void* d_out, int out_size, void* d_ws, size_t ws_size,
                              hipStream_t stream) {
  (void)in_sizes; (void)n_in; (void)out_size; (void)ws_size;
  const float* features = (const float*)d_in[0];
  const float* pe = (const float*)d_in[1];
  char* ws = (char*)d_ws;
  float* Pp       = (float*)(ws);                  // 16*8*256*256*4 = 32 MiB
  float* Db       = (float*)(ws + 33554432);       // 2 MiB
  float* rs       = (float*)(ws + 35651584);       // 8 KiB
  float* centers0 = (float*)(ws + 35659776);       // 192 B
  float* ccoord   = (float*)(ws + 35660288);       // 1.5 KiB
  int*   outp     = (int*)d_out;

  hipLaunchKernelGGL(k_gemm_pre, dim3(GEMM_BLOCKS + 1), dim3(256), 0, stream,
                     features, pe, Pp, centers0, rs);
  hipLaunchKernelGGL(k_formD, dim3(256), dim3(256), 0, stream, Pp, Db, rs);
  hipLaunchKernelGGL(k_fps_b, dim3(NB), dim3(256), 0, stream, Db, rs, pe, ccoord);
  hipLaunchKernelGGL(k_final, dim3(1), dim3(256), 0, stream, pe, ccoord, centers0, outp);
}